// Round 3
// baseline (379.245 us; speedup 1.0000x reference)
//
#include <hip/hip_runtime.h>
#include <hip/hip_fp16.h>

#define DD 192
#define HH 192
#define WW 192
#define NVOX (DD * HH * WW)

#define TS 16                  // tile edge (voxels per block per dim)
#define HL 8                   // halo each side (+1 upper corner)
#define RS (TS + 2 * HL + 1)   // 33
#define RS2 (RS * RS)          // 1089
#define RSIZE (RS * RS * RS)   // 35937 halves = 70.2 KB
#define NBLK (12 * 12 * 12)

__global__ __launch_bounds__(1024) void warp_mse_tiled(
    const float* __restrict__ mov,
    const float* __restrict__ vf,
    const float* __restrict__ fix,
    const int* __restrict__ mask,
    float* __restrict__ acc,   // acc[0]=sum(sq*m), acc[1]=sum(m), acc[2]=done counter
    float* __restrict__ out)
{
    __shared__ __half smov[RSIZE];
    __shared__ float s_sq[16], s_cnt[16];

    const int tid = threadIdx.x;
    const int bx0 = blockIdx.x * TS;
    const int by0 = blockIdx.y * TS;
    const int bz0 = blockIdx.z * TS;
    const int z_lo = bz0 - HL, y_lo = by0 - HL, x_lo = bx0 - HL;

    // ---- stage mov region into LDS as fp16, zero-padded outside volume ----
    // tid -> (ry,rx) decomposed ONCE; loop over 33 z-slabs with incremental addrs.
    {
        const int i1 = tid;                       // 0..1023
        const int ry1 = i1 / RS, rx1 = i1 - ry1 * RS;
        const int gy1 = y_lo + ry1, gx1 = x_lo + rx1;
        const bool vxy1 = ((unsigned)gy1 < HH) & ((unsigned)gx1 < WW);
        const int i2 = 1024 + tid;                // leftover 1024..1088
        const bool has2 = (i2 < RS2);
        const int ry2 = i2 / RS, rx2 = i2 - ry2 * RS;
        const int gy2 = y_lo + ry2, gx2 = x_lo + rx2;
        const bool vxy2 = has2 && ((unsigned)gy2 < HH) & ((unsigned)gx2 < WW);

        #pragma unroll 4
        for (int rz = 0; rz < RS; ++rz) {
            const int gz = z_lo + rz;
            const bool vz = (unsigned)gz < DD;
            float v1 = 0.0f, v2 = 0.0f;
            if (vz & vxy1) v1 = mov[(gz * HH + gy1) * WW + gx1];
            if (vz & vxy2) v2 = mov[(gz * HH + gy2) * WW + gx2];
            smov[rz * RS2 + i1] = __float2half(v1);
            if (has2) smov[rz * RS2 + i2] = __float2half(v2);
        }
    }
    __syncthreads();

    // ---- compute: each thread handles 4 consecutive-x voxels ----
    const int lxg = (tid & 3) * 4;
    const int ly  = (tid >> 2) & 15;
    const int lz  = tid >> 6;
    const int gz = bz0 + lz;
    const int gy = by0 + ly;
    const int gx0 = bx0 + lxg;
    const int base = (gz * HH + gy) * WW + gx0;

    const float4 dz4 = *(const float4*)(vf + base);
    const float4 dy4 = *(const float4*)(vf + NVOX + base);
    const float4 dx4 = *(const float4*)(vf + 2 * NVOX + base);
    const float4 f4  = *(const float4*)(fix + base);
    const int4   m4  = *(const int4*)(mask + base);

    const float dzv[4] = {dz4.x, dz4.y, dz4.z, dz4.w};
    const float dyv[4] = {dy4.x, dy4.y, dy4.z, dy4.w};
    const float dxv[4] = {dx4.x, dx4.y, dx4.z, dx4.w};
    const float fv[4]  = {f4.x, f4.y, f4.z, f4.w};
    const int   mv[4]  = {m4.x, m4.y, m4.z, m4.w};

    float sq = 0.0f, cnt = 0.0f;

    #pragma unroll
    for (int j = 0; j < 4; ++j) {
        const float z = (float)gz + dzv[j];
        const float y = (float)gy + dyv[j];
        const float x = (float)(gx0 + j) + dxv[j];

        const float z0f = floorf(z), y0f = floorf(y), x0f = floorf(x);
        const float wz = z - z0f, wy = y - y0f, wx = x - x0f;
        const int z0 = (int)z0f, y0 = (int)y0f, x0 = (int)x0f;

        const int z0l = z0 - z_lo, y0l = y0 - y_lo, x0l = x0 - x_lo;
        const bool inbox = ((unsigned)z0l < RS - 1) & ((unsigned)y0l < RS - 1) &
                           ((unsigned)x0l < RS - 1);

        float v000, v001, v010, v011, v100, v101, v110, v111;
        if (inbox) {
            const int o = z0l * RS2 + y0l * RS + x0l;
            v000 = __half2float(smov[o]);
            v001 = __half2float(smov[o + 1]);
            v010 = __half2float(smov[o + RS]);
            v011 = __half2float(smov[o + RS + 1]);
            v100 = __half2float(smov[o + RS2]);
            v101 = __half2float(smov[o + RS2 + 1]);
            v110 = __half2float(smov[o + RS2 + RS]);
            v111 = __half2float(smov[o + RS2 + RS + 1]);
        } else {
            // rare: displacement beyond halo — full-precision global fallback
            const int z1 = z0 + 1, y1 = y0 + 1, x1 = x0 + 1;
            const bool zi0 = (unsigned)z0 < DD, zi1 = (unsigned)z1 < DD;
            const bool yi0 = (unsigned)y0 < HH, yi1 = (unsigned)y1 < HH;
            const bool xi0 = (unsigned)x0 < WW, xi1 = (unsigned)x1 < WW;
            auto ld = [&](int iz, int iy, int ix, bool ok) -> float {
                return ok ? mov[(iz * HH + iy) * WW + ix] : 0.0f;
            };
            v000 = ld(z0, y0, x0, zi0 & yi0 & xi0);
            v001 = ld(z0, y0, x1, zi0 & yi0 & xi1);
            v010 = ld(z0, y1, x0, zi0 & yi1 & xi0);
            v011 = ld(z0, y1, x1, zi0 & yi1 & xi1);
            v100 = ld(z1, y0, x0, zi1 & yi0 & xi0);
            v101 = ld(z1, y0, x1, zi1 & yi0 & xi1);
            v110 = ld(z1, y1, x0, zi1 & yi1 & xi0);
            v111 = ld(z1, y1, x1, zi1 & yi1 & xi1);
        }

        const float c00 = v000 + (v001 - v000) * wx;
        const float c01 = v010 + (v011 - v010) * wx;
        const float c10 = v100 + (v101 - v100) * wx;
        const float c11 = v110 + (v111 - v110) * wx;
        const float c0 = c00 + (c01 - c00) * wy;
        const float c1 = c10 + (c11 - c10) * wy;
        const float warped = c0 + (c1 - c0) * wz;

        const float m = (mv[j] != 0) ? 1.0f : 0.0f;
        const float diff = warped - fv[j];
        sq += diff * diff * m;
        cnt += m;
    }

    // ---- reduction: wave64 shuffle -> LDS -> one atomic pair per block ----
    #pragma unroll
    for (int off = 32; off > 0; off >>= 1) {
        sq  += __shfl_down(sq, off, 64);
        cnt += __shfl_down(cnt, off, 64);
    }
    const int lane = tid & 63;
    const int wid = tid >> 6;
    if (lane == 0) { s_sq[wid] = sq; s_cnt[wid] = cnt; }
    __syncthreads();
    if (tid == 0) {
        float bsq = 0.0f, bcnt = 0.0f;
        #pragma unroll
        for (int i = 0; i < 16; ++i) { bsq += s_sq[i]; bcnt += s_cnt[i]; }
        atomicAdd(&acc[0], bsq);
        atomicAdd(&acc[1], bcnt);
        __threadfence();
        const unsigned old = atomicAdd((unsigned*)&acc[2], 1u);
        if (old == NBLK - 1) {
            __threadfence();
            const float s = atomicAdd(&acc[0], 0.0f);   // coherent read
            const float c = atomicAdd(&acc[1], 0.0f);
            out[0] = s / fmaxf(c, 1.0f);
        }
    }
}

extern "C" void kernel_launch(void* const* d_in, const int* in_sizes, int n_in,
                              void* d_out, int out_size, void* d_ws, size_t ws_size,
                              hipStream_t stream) {
    const float* mov  = (const float*)d_in[0];
    const float* vf   = (const float*)d_in[1];
    const float* fix  = (const float*)d_in[2];
    const int*   mask = (const int*)d_in[3];
    float* acc = (float*)d_ws;
    float* out = (float*)d_out;

    hipMemsetAsync(d_ws, 0, 4 * sizeof(float), stream);

    dim3 grid(WW / TS, HH / TS, DD / TS);  // 12 x 12 x 12 = 1728 blocks
    warp_mse_tiled<<<grid, 1024, 0, stream>>>(mov, vf, fix, mask, acc, out);
}